// Round 6
// baseline (93.198 us; speedup 1.0000x reference)
//
#include <hip/hip_runtime.h>
#include <cstdint>

typedef __attribute__((ext_vector_type(4))) int i32x4;

#define XROWS  22
#define ROWB   2048              // LDS bytes per staged row (w 0..31, 64B each)
#define WSLICE 8192
#define WB_BYTES 409600          // wb (401408) + padding; counter at 401408
#define CTR_OFF  401408
#define XT_BYTES ((size_t)16 * 112 * 128 * 64)
#define NTILES 1568
#define PERSIST_BLOCKS 768       // 3 blocks/CU x 256 CU

__device__ __forceinline__ void g2lds16(const void* g, void* l) {
  __builtin_amdgcn_global_load_lds(
      (const __attribute__((address_space(1))) unsigned int*)g,
      (__attribute__((address_space(3))) unsigned int*)l, 16, 0, 0);
}

// ---- standalone W pack (fallback path): wb[((s*4+g)*128+co)*16+lo], s=kh*7+kw
__global__ void prep_w(const float* __restrict__ w1,
                       const float* __restrict__ w2,
                       const float* __restrict__ w3,
                       signed char* __restrict__ wb) {
  int t = blockIdx.x * 256 + threadIdx.x;
  int lo = t & 15;
  int co = (t >> 4) & 127;
  int g  = (t >> 11) & 3;
  int s  = t >> 13;
  if (s >= 49) return;
  int kh = s / 7, kw = s % 7;
  int ci = g * 16 + lo;
  int base = ((co * 64 + ci) * 7 + kh) * 3;
  float v;
  if (kw < 3)       v = w1[base + kw];
  else if (kw == 3) v = w2[base + 1];
  else              v = w3[base + kw - 4];
  wb[t] = (signed char)(int)v;
}

// ---- merged prep: X pre-transpose + W pack + steal-counter zero.
// xt[n][h][w(128)][ci(64)] i8, clamped, 16B-granule-swizzled (granule p holds
// ci-granule p ^ ((w>>1)&3)).
__global__ void prep_xw(const int* __restrict__ x,
                        const float* __restrict__ w1,
                        const float* __restrict__ w2,
                        const float* __restrict__ w3,
                        signed char* __restrict__ xt,
                        signed char* __restrict__ wb,
                        unsigned int* __restrict__ ctr) {
  __shared__ unsigned char T[64 * 68];
  const int tid = threadIdx.x;
  const int wt = blockIdx.x * 64, h = blockIdx.y, n = blockIdx.z;
  const int fid = (blockIdx.z * 112 + blockIdx.y) * 2 + blockIdx.x;

  if (fid == 0 && tid == 0) *ctr = 0;            // re-armed every launch/replay

  if (fid < 1568) {                              // W pack: 1568*256 = 401408 elems
    int t = fid * 256 + tid;
    int lo = t & 15;
    int co = (t >> 4) & 127;
    int g  = (t >> 11) & 3;
    int s  = t >> 13;
    int kh = s / 7, kw = s % 7;
    int ci = g * 16 + lo;
    int base = ((co * 64 + ci) * 7 + kh) * 3;
    float v;
    if (kw < 3)       v = w1[base + kw];
    else if (kw == 3) v = w2[base + 1];
    else              v = w3[base + kw - 4];
    wb[t] = (signed char)(int)v;
  }

  {
    const int wr = tid & 63;
    const int cb = (tid >> 6) * 16;
    int ws = wt + wr; ws = ws < 112 ? ws : 111;
    const int* xp = x + (((size_t)n * 64 + cb) * 112 + h) * 112 + ws;
    #pragma unroll
    for (int g4 = 0; g4 < 4; ++g4) {
      uint32_t v = 0;
      #pragma unroll
      for (int j = 0; j < 4; ++j) {
        int a = xp[(g4 * 4 + j) * 12544];
        a = a < 0 ? 0 : (a > 7 ? 7 : a);
        v |= (uint32_t)a << (8 * j);
      }
      *(uint32_t*)&T[wr * 68 + cb + g4 * 4] = v;
    }
  }
  __syncthreads();
  {
    const int wo = tid >> 2, q = tid & 3;
    const int key = ((wt + wo) >> 1) & 3;
    const int sg = (q ^ key) << 4;
    int4 v;
    v.x = *(const int*)&T[wo * 68 + sg + 0];
    v.y = *(const int*)&T[wo * 68 + sg + 4];
    v.z = *(const int*)&T[wo * 68 + sg + 8];
    v.w = *(const int*)&T[wo * 68 + sg + 12];
    *(int4*)&xt[(((size_t)n * 112 + h) * 128 + wt + wo) * 64 + q * 16] = v;
  }
}

#define MFMA(acc, a, b) acc = __builtin_amdgcn_mfma_i32_16x16x64_i8(a, b, acc, 0, 0, 0)

// ---- persistent work-stealing conv: 768 blocks loop over 1568 tiles
__global__ __launch_bounds__(256, 3)
void conv7p(const signed char* __restrict__ xt,
            const signed char* __restrict__ wb,
            float* __restrict__ out,
            unsigned int* __restrict__ ctr) {
  __shared__ __align__(16) unsigned char Xs[XROWS * ROWB];   // 45056 B
  __shared__ unsigned int ts;

  const int tid  = threadIdx.x;
  const int lane = tid & 63;
  const int wid  = tid >> 6;               // wave = spatial quarter (4 ho rows)
  const int lrow = lane & 15;
  const int lkg  = lane >> 4;
  const int rowB = wid * 4;

  for (;;) {
    if (tid == 0) ts = atomicAdd(ctr, 1u);
    __syncthreads();                       // publishes ts AND protects Xs reuse
    const unsigned int t = ts;
    if (t >= NTILES) break;

    const int coh = t & 1;                 // co-halves adjacent in steal order
    const int r2  = t >> 1;
    const int bx  = r2 % 7;
    const int t7  = r2 / 7;
    const int by  = t7 % 7;
    const int n   = t7 / 7;
    const int ho_base = by * 16;
    const int wo_base = bx * 16;

    const signed char* aB = wb + lkg * 2048 + coh * 1024 + lrow * 16;
    i32x4 A[4];
    #pragma unroll
    for (int m = 0; m < 4; ++m) A[m] = *(const i32x4*)(aB + m * 256);  // slice 0

    for (int r = wid; r < XROWS; r += 4) {
      int h = ho_base + r; h = h < 112 ? h : 111;   // clamped rows feed only masked outputs
      const signed char* src = xt + (((size_t)n * 112 + h) * 128 + wo_base) * 64;
      g2lds16(src + lane * 16, &Xs[r * ROWB]);
      g2lds16(src + 1024 + lane * 16, &Xs[r * ROWB + 1024]);
    }
    asm volatile("s_waitcnt vmcnt(0)" ::: "memory");
    __syncthreads();

    i32x4 acc[4][4];
    #pragma unroll
    for (int m = 0; m < 4; ++m)
      #pragma unroll
      for (int b = 0; b < 4; ++b)
        acc[m][b] = (i32x4){0, 0, 0, 0};

    for (int kw = 0; kw < 7; ++kw) {
      const int w_l  = lrow + kw;
      const int bcol = w_l * 64 + ((lkg ^ ((w_l >> 1) & 3)) << 4);
      i32x4 B[8];
      #pragma unroll
      for (int b = 0; b < 4; ++b)
        B[b] = *(const i32x4*)&Xs[(rowB + b) * ROWB + bcol];

      #pragma unroll
      for (int kh = 0; kh < 7; ++kh) {
        if (kh < 6)                        // row kh+4 into free slot, consumed next kh
          B[(kh + 4) & 7] = *(const i32x4*)&Xs[(rowB + kh + 4) * ROWB + bcol];
        const signed char* apn = aB + (size_t)(kh < 6 ? (kh + 1) * 7 + kw : kw + 1) * WSLICE;
        __builtin_amdgcn_s_setprio(1);
        #pragma unroll
        for (int m = 0; m < 4; ++m) {
          #pragma unroll
          for (int b = 0; b < 4; ++b)
            MFMA(acc[m][b], A[m], B[(kh + b) & 7]);
          A[m] = *(const i32x4*)(apn + m * 256);   // staggered in-place reload
        }
        __builtin_amdgcn_s_setprio(0);
      }
    }

    // epilogue: C/D map col=lane&15 (wo), row=(lane>>4)*4+j (co); i32->f32 exact
    const int wo = wo_base + lrow;
    if (wo < 106) {
      #pragma unroll
      for (int m = 0; m < 4; ++m) {
        const int co = coh * 64 + m * 16 + lkg * 4;
        #pragma unroll
        for (int b = 0; b < 4; ++b) {
          const int ho = ho_base + rowB + b;
          if (ho < 106) {
            float* op = out + (((size_t)n * 128 + co) * 106 + ho) * 106 + wo;
            #pragma unroll
            for (int j = 0; j < 4; ++j)
              op[(size_t)j * 11236] = (float)acc[m][b][j];
          }
        }
      }
    }
  }
}

// ---- fallback (small ws): static grid, stages straight from NCHW x
__global__ __launch_bounds__(256, 3)
void conv7f(const int* __restrict__ x,
            const signed char* __restrict__ wb, float* __restrict__ out) {
  __shared__ __align__(16) unsigned char Xs[XROWS * ROWB];

  const int tid  = threadIdx.x;
  const int lane = tid & 63;
  const int wid  = tid >> 6;
  const int lrow = lane & 15;
  const int lkg  = lane >> 4;

  const int L  = blockIdx.x;
  const int Lp = (L & 7) * 196 + (L >> 3);
  const int coh = Lp & 1;
  const int r2  = Lp >> 1;
  const int bx  = r2 % 7;
  const int t7  = r2 / 7;
  const int by  = t7 % 7;
  const int n   = t7 / 7;
  const int ho_base = by * 16;
  const int wo_base = bx * 16;

  const signed char* aB = wb + lkg * 2048 + coh * 1024 + lrow * 16;
  i32x4 A[4];
  #pragma unroll
  for (int m = 0; m < 4; ++m) A[m] = *(const i32x4*)(aB + m * 256);

  {
    const int w_a  = tid & 15,       cg_a  = tid >> 4;
    const int w_b2 = 16 + (tid & 7), cg_b2 = tid >> 3;
    const bool doB = (tid < 128) && ((tid & 7) < 6);
    const int keyA = ((w_a >> 1) & 3) << 2;
    const int keyB = ((w_b2 >> 1) & 3) << 2;
    for (int r = 0; r < XROWS; ++r) {
      int h = ho_base + r; h = h < 112 ? h : 111;
      const int* xr = x + (size_t)n * 64 * 12544 + h * 112;
      {
        int wc = wo_base + w_a; wc = wc < 112 ? wc : 111;
        uint32_t v = 0;
        #pragma unroll
        for (int j = 0; j < 4; ++j) {
          int a = xr[(cg_a * 4 + j) * 12544 + wc];
          a = a < 0 ? 0 : (a > 7 ? 7 : a);
          v |= (uint32_t)a << (8 * j);
        }
        *(uint32_t*)&Xs[r * ROWB + w_a * 64 + ((cg_a ^ keyA) << 2)] = v;
      }
      if (doB) {
        int wc = wo_base + w_b2; wc = wc < 112 ? wc : 111;
        uint32_t v = 0;
        #pragma unroll
        for (int j = 0; j < 4; ++j) {
          int a = xr[(cg_b2 * 4 + j) * 12544 + wc];
          a = a < 0 ? 0 : (a > 7 ? 7 : a);
          v |= (uint32_t)a << (8 * j);
        }
        *(uint32_t*)&Xs[r * ROWB + w_b2 * 64 + ((cg_b2 ^ keyB) << 2)] = v;
      }
    }
  }
  __syncthreads();

  i32x4 acc[4][4];
  #pragma unroll
  for (int m = 0; m < 4; ++m)
    #pragma unroll
    for (int b = 0; b < 4; ++b)
      acc[m][b] = (i32x4){0, 0, 0, 0};

  const int rowB = wid * 4;

  for (int kw = 0; kw < 7; ++kw) {
    const int w_l  = lrow + kw;
    const int bcol = w_l * 64 + ((lkg ^ ((w_l >> 1) & 3)) << 4);
    i32x4 B[8];
    #pragma unroll
    for (int b = 0; b < 4; ++b)
      B[b] = *(const i32x4*)&Xs[(rowB + b) * ROWB + bcol];
    #pragma unroll
    for (int kh = 0; kh < 7; ++kh) {
      if (kh < 6)
        B[(kh + 4) & 7] = *(const i32x4*)&Xs[(rowB + kh + 4) * ROWB + bcol];
      const signed char* apn = aB + (size_t)(kh < 6 ? (kh + 1) * 7 + kw : kw + 1) * WSLICE;
      #pragma unroll
      for (int m = 0; m < 4; ++m) {
        #pragma unroll
        for (int b = 0; b < 4; ++b)
          MFMA(acc[m][b], A[m], B[(kh + b) & 7]);
        A[m] = *(const i32x4*)(apn + m * 256);
      }
    }
  }

  const int wo = wo_base + lrow;
  if (wo < 106) {
    #pragma unroll
    for (int m = 0; m < 4; ++m) {
      const int co = coh * 64 + m * 16 + lkg * 4;
      #pragma unroll
      for (int b = 0; b < 4; ++b) {
        const int ho = ho_base + rowB + b;
        if (ho < 106) {
          float* op = out + (((size_t)n * 128 + co) * 106 + ho) * 106 + wo;
          #pragma unroll
          for (int j = 0; j < 4; ++j)
            op[(size_t)j * 11236] = (float)acc[m][b][j];
        }
      }
    }
  }
}

extern "C" void kernel_launch(void* const* d_in, const int* in_sizes, int n_in,
                              void* d_out, int out_size, void* d_ws, size_t ws_size,
                              hipStream_t stream) {
  const int*   x  = (const int*)d_in[0];
  const float* w1 = (const float*)d_in[1];
  const float* w2 = (const float*)d_in[2];
  const float* w3 = (const float*)d_in[3];
  float* outp = (float*)d_out;
  signed char* wbp = (signed char*)d_ws;
  signed char* xtp = wbp + WB_BYTES;
  unsigned int* ctr = (unsigned int*)(wbp + CTR_OFF);

  if (ws_size >= WB_BYTES + XT_BYTES) {
    prep_xw<<<dim3(2, 112, 16), dim3(256), 0, stream>>>(x, w1, w2, w3, xtp, wbp, ctr);
    conv7p<<<dim3(PERSIST_BLOCKS), dim3(256), 0, stream>>>(xtp, wbp, outp, ctr);
  } else {
    prep_w<<<dim3(1568), dim3(256), 0, stream>>>(w1, w2, w3, wbp);
    conv7f<<<dim3(1568), dim3(256), 0, stream>>>(x, wbp, outp);
  }
}

// Round 7
// 75.034 us; speedup vs baseline: 1.2421x; 1.2421x over previous
//
#include <hip/hip_runtime.h>
#include <cstdint>

typedef __attribute__((ext_vector_type(4))) int i32x4;

#define XROWS  22
#define ROWB   2048              // LDS bytes per staged row (w 0..31, 64B each)
#define WSLICE 8192
#define WB_BYTES 409600          // wb (401408) rounded up
#define XT_BYTES ((size_t)16 * 112 * 128 * 64)
#define NTILES 1568
#define GRID_MAIN 1536           // 2 exact layers at 3 blocks/CU; first 32 blocks dual

__device__ __forceinline__ void g2lds16(const void* g, void* l) {
  __builtin_amdgcn_global_load_lds(
      (const __attribute__((address_space(1))) unsigned int*)g,
      (__attribute__((address_space(3))) unsigned int*)l, 16, 0, 0);
}

// ---- standalone W pack (fallback path): wb[((s*4+g)*128+co)*16+lo], s=kh*7+kw
__global__ void prep_w(const float* __restrict__ w1,
                       const float* __restrict__ w2,
                       const float* __restrict__ w3,
                       signed char* __restrict__ wb) {
  int t = blockIdx.x * 256 + threadIdx.x;
  int lo = t & 15;
  int co = (t >> 4) & 127;
  int g  = (t >> 11) & 3;
  int s  = t >> 13;
  if (s >= 49) return;
  int kh = s / 7, kw = s % 7;
  int ci = g * 16 + lo;
  int base = ((co * 64 + ci) * 7 + kh) * 3;
  float v;
  if (kw < 3)       v = w1[base + kw];
  else if (kw == 3) v = w2[base + 1];
  else              v = w3[base + kw - 4];
  wb[t] = (signed char)(int)v;
}

// ---- merged prep: X pre-transpose + W pack.
// xt[n][h][w(128)][ci(64)] i8, clamped, 16B-granule-swizzled (granule p holds
// ci-granule p ^ ((w>>1)&3)).
__global__ void prep_xw(const int* __restrict__ x,
                        const float* __restrict__ w1,
                        const float* __restrict__ w2,
                        const float* __restrict__ w3,
                        signed char* __restrict__ xt,
                        signed char* __restrict__ wb) {
  __shared__ unsigned char T[64 * 68];
  const int tid = threadIdx.x;
  const int wt = blockIdx.x * 64, h = blockIdx.y, n = blockIdx.z;
  const int fid = (blockIdx.z * 112 + blockIdx.y) * 2 + blockIdx.x;

  if (fid < 1568) {                              // W pack: 1568*256 = 401408 elems
    int t = fid * 256 + tid;
    int lo = t & 15;
    int co = (t >> 4) & 127;
    int g  = (t >> 11) & 3;
    int s  = t >> 13;
    int kh = s / 7, kw = s % 7;
    int ci = g * 16 + lo;
    int base = ((co * 64 + ci) * 7 + kh) * 3;
    float v;
    if (kw < 3)       v = w1[base + kw];
    else if (kw == 3) v = w2[base + 1];
    else              v = w3[base + kw - 4];
    wb[t] = (signed char)(int)v;
  }

  {
    const int wr = tid & 63;
    const int cb = (tid >> 6) * 16;
    int ws = wt + wr; ws = ws < 112 ? ws : 111;
    const int* xp = x + (((size_t)n * 64 + cb) * 112 + h) * 112 + ws;
    #pragma unroll
    for (int g4 = 0; g4 < 4; ++g4) {
      uint32_t v = 0;
      #pragma unroll
      for (int j = 0; j < 4; ++j) {
        int a = xp[(g4 * 4 + j) * 12544];
        a = a < 0 ? 0 : (a > 7 ? 7 : a);
        v |= (uint32_t)a << (8 * j);
      }
      *(uint32_t*)&T[wr * 68 + cb + g4 * 4] = v;
    }
  }
  __syncthreads();
  {
    const int wo = tid >> 2, q = tid & 3;
    const int key = ((wt + wo) >> 1) & 3;
    const int sg = (q ^ key) << 4;
    int4 v;
    v.x = *(const int*)&T[wo * 68 + sg + 0];
    v.y = *(const int*)&T[wo * 68 + sg + 4];
    v.z = *(const int*)&T[wo * 68 + sg + 8];
    v.w = *(const int*)&T[wo * 68 + sg + 12];
    *(int4*)&xt[(((size_t)n * 112 + h) * 128 + wt + wo) * 64 + q * 16] = v;
  }
}

#define MFMA(acc, a, b) acc = __builtin_amdgcn_mfma_i32_16x16x64_i8(a, b, acc, 0, 0, 0)

// ---- main conv: static grid 1536, blocks 0..31 run a second tile.
// Waves: [2 co x 2 sp] -> wave = co32 x 8ho x 16wo; A dup 2x (was 4x).
__global__ __launch_bounds__(256, 3)
void conv7s(const signed char* __restrict__ xt,
            const signed char* __restrict__ wb,
            float* __restrict__ out) {
  __shared__ __align__(16) unsigned char Xs[XROWS * ROWB];   // 45056 B

  const int tid  = threadIdx.x;
  const int lane = tid & 63;
  const int wid  = tid >> 6;
  const int lrow = lane & 15;
  const int lkg  = lane >> 4;
  const int cop  = wid >> 1;               // co quarter-pair (co32) within co64
  const int sph  = wid & 1;                // ho half (8 rows)
  const int rowB = sph * 8;

  // bijective XCD chunking: 1536 = 8 * 192
  const int L  = blockIdx.x;
  const int Lp = (L & 7) * 192 + (L >> 3);
  const int npass = (L < 32) ? 2 : 1;

  for (int pass = 0; pass < npass; ++pass) {
    const int t = (pass == 0) ? Lp : (GRID_MAIN + L);   // tiles 1536..1567 on dual blocks
    const int coh = t & 1;
    const int r2  = t >> 1;
    const int bx  = r2 % 7;
    const int t7  = r2 / 7;
    const int by  = t7 % 7;
    const int n   = t7 / 7;
    const int ho_base = by * 16;
    const int wo_base = bx * 16;

    const signed char* aB = wb + lkg * 2048 + (coh * 64 + cop * 32 + lrow) * 16;
    i32x4 A[2];
    #pragma unroll
    for (int m = 0; m < 2; ++m) A[m] = *(const i32x4*)(aB + m * 256);  // slice 0

    if (pass) __syncthreads();             // protect Xs reuse across passes

    for (int r = wid; r < XROWS; r += 4) {
      int h = ho_base + r; h = h < 112 ? h : 111;   // clamped rows feed only masked outputs
      const signed char* src = xt + (((size_t)n * 112 + h) * 128 + wo_base) * 64;
      g2lds16(src + lane * 16, &Xs[r * ROWB]);
      g2lds16(src + 1024 + lane * 16, &Xs[r * ROWB + 1024]);
    }
    asm volatile("s_waitcnt vmcnt(0)" ::: "memory");
    __syncthreads();

    i32x4 acc[2][8];
    #pragma unroll
    for (int m = 0; m < 2; ++m)
      #pragma unroll
      for (int b = 0; b < 8; ++b)
        acc[m][b] = (i32x4){0, 0, 0, 0};

    for (int kw = 0; kw < 7; ++kw) {
      const int w_l  = lrow + kw;
      const int bcol = w_l * 64 + ((lkg ^ ((w_l >> 1) & 3)) << 4);
      i32x4 B[8];
      #pragma unroll
      for (int b = 0; b < 8; ++b)
        B[b] = *(const i32x4*)&Xs[(rowB + b) * ROWB + bcol];   // rows rowB..rowB+7

      #pragma unroll
      for (int kh = 0; kh < 7; ++kh) {
        // slots hold rows rowB+kh .. rowB+kh+7 at slot (row-rowB)&7
        const signed char* apn = aB + (size_t)(kh < 6 ? (kh + 1) * 7 + kw : kw + 1) * WSLICE;
        __builtin_amdgcn_s_setprio(1);
        #pragma unroll
        for (int m = 0; m < 2; ++m) {
          #pragma unroll
          for (int b = 0; b < 8; ++b)
            MFMA(acc[m][b], A[m], B[(kh + b) & 7]);
          A[m] = *(const i32x4*)(apn + m * 256);   // staggered in-place reload
        }
        __builtin_amdgcn_s_setprio(0);
        if (kh < 6)                          // row rowB+kh dead; bring in rowB+kh+8
          B[kh & 7] = *(const i32x4*)&Xs[(rowB + kh + 8) * ROWB + bcol];
      }
    }

    // epilogue: C/D map col=lane&15 (wo), row=(lane>>4)*4+j (co); i32->f32 exact
    const int wo = wo_base + lrow;
    if (wo < 106) {
      #pragma unroll
      for (int m = 0; m < 2; ++m) {
        const int co = coh * 64 + cop * 32 + m * 16 + lkg * 4;
        #pragma unroll
        for (int b = 0; b < 8; ++b) {
          const int ho = ho_base + rowB + b;
          if (ho < 106) {
            float* op = out + (((size_t)n * 128 + co) * 106 + ho) * 106 + wo;
            #pragma unroll
            for (int j = 0; j < 4; ++j)
              op[(size_t)j * 11236] = (float)acc[m][b][j];
          }
        }
      }
    }
  }
}

// ---- fallback (small ws): static grid 1568, stages straight from NCHW x
__global__ __launch_bounds__(256, 3)
void conv7f(const int* __restrict__ x,
            const signed char* __restrict__ wb, float* __restrict__ out) {
  __shared__ __align__(16) unsigned char Xs[XROWS * ROWB];

  const int tid  = threadIdx.x;
  const int lane = tid & 63;
  const int wid  = tid >> 6;
  const int lrow = lane & 15;
  const int lkg  = lane >> 4;

  const int L  = blockIdx.x;
  const int Lp = (L & 7) * 196 + (L >> 3);
  const int coh = Lp & 1;
  const int r2  = Lp >> 1;
  const int bx  = r2 % 7;
  const int t7  = r2 / 7;
  const int by  = t7 % 7;
  const int n   = t7 / 7;
  const int ho_base = by * 16;
  const int wo_base = bx * 16;

  const signed char* aB = wb + lkg * 2048 + coh * 1024 + lrow * 16;
  i32x4 A[4];
  #pragma unroll
  for (int m = 0; m < 4; ++m) A[m] = *(const i32x4*)(aB + m * 256);

  {
    const int w_a  = tid & 15,       cg_a  = tid >> 4;
    const int w_b2 = 16 + (tid & 7), cg_b2 = tid >> 3;
    const bool doB = (tid < 128) && ((tid & 7) < 6);
    const int keyA = ((w_a >> 1) & 3) << 2;
    const int keyB = ((w_b2 >> 1) & 3) << 2;
    for (int r = 0; r < XROWS; ++r) {
      int h = ho_base + r; h = h < 112 ? h : 111;
      const int* xr = x + (size_t)n * 64 * 12544 + h * 112;
      {
        int wc = wo_base + w_a; wc = wc < 112 ? wc : 111;
        uint32_t v = 0;
        #pragma unroll
        for (int j = 0; j < 4; ++j) {
          int a = xr[(cg_a * 4 + j) * 12544 + wc];
          a = a < 0 ? 0 : (a > 7 ? 7 : a);
          v |= (uint32_t)a << (8 * j);
        }
        *(uint32_t*)&Xs[r * ROWB + w_a * 64 + ((cg_a ^ keyA) << 2)] = v;
      }
      if (doB) {
        int wc = wo_base + w_b2; wc = wc < 112 ? wc : 111;
        uint32_t v = 0;
        #pragma unroll
        for (int j = 0; j < 4; ++j) {
          int a = xr[(cg_b2 * 4 + j) * 12544 + wc];
          a = a < 0 ? 0 : (a > 7 ? 7 : a);
          v |= (uint32_t)a << (8 * j);
        }
        *(uint32_t*)&Xs[r * ROWB + w_b2 * 64 + ((cg_b2 ^ keyB) << 2)] = v;
      }
    }
  }
  __syncthreads();

  i32x4 acc[4][4];
  #pragma unroll
  for (int m = 0; m < 4; ++m)
    #pragma unroll
    for (int b = 0; b < 4; ++b)
      acc[m][b] = (i32x4){0, 0, 0, 0};

  const int rowB = wid * 4;

  for (int kw = 0; kw < 7; ++kw) {
    const int w_l  = lrow + kw;
    const int bcol = w_l * 64 + ((lkg ^ ((w_l >> 1) & 3)) << 4);
    i32x4 B[8];
    #pragma unroll
    for (int b = 0; b < 4; ++b)
      B[b] = *(const i32x4*)&Xs[(rowB + b) * ROWB + bcol];
    #pragma unroll
    for (int kh = 0; kh < 7; ++kh) {
      if (kh < 6)
        B[(kh + 4) & 7] = *(const i32x4*)&Xs[(rowB + kh + 4) * ROWB + bcol];
      const signed char* apn = aB + (size_t)(kh < 6 ? (kh + 1) * 7 + kw : kw + 1) * WSLICE;
      #pragma unroll
      for (int m = 0; m < 4; ++m) {
        #pragma unroll
        for (int b = 0; b < 4; ++b)
          MFMA(acc[m][b], A[m], B[(kh + b) & 7]);
        A[m] = *(const i32x4*)(apn + m * 256);
      }
    }
  }

  const int wo = wo_base + lrow;
  if (wo < 106) {
    #pragma unroll
    for (int m = 0; m < 4; ++m) {
      const int co = coh * 64 + m * 16 + lkg * 4;
      #pragma unroll
      for (int b = 0; b < 4; ++b) {
        const int ho = ho_base + rowB + b;
        if (ho < 106) {
          float* op = out + (((size_t)n * 128 + co) * 106 + ho) * 106 + wo;
          #pragma unroll
          for (int j = 0; j < 4; ++j)
            op[(size_t)j * 11236] = (float)acc[m][b][j];
        }
      }
    }
  }
}

extern "C" void kernel_launch(void* const* d_in, const int* in_sizes, int n_in,
                              void* d_out, int out_size, void* d_ws, size_t ws_size,
                              hipStream_t stream) {
  const int*   x  = (const int*)d_in[0];
  const float* w1 = (const float*)d_in[1];
  const float* w2 = (const float*)d_in[2];
  const float* w3 = (const float*)d_in[3];
  float* outp = (float*)d_out;
  signed char* wbp = (signed char*)d_ws;
  signed char* xtp = wbp + WB_BYTES;

  if (ws_size >= WB_BYTES + XT_BYTES) {
    prep_xw<<<dim3(2, 112, 16), dim3(256), 0, stream>>>(x, w1, w2, w3, xtp, wbp);
    conv7s<<<dim3(GRID_MAIN), dim3(256), 0, stream>>>(xtp, wbp, outp);
  } else {
    prep_w<<<dim3(1568), dim3(256), 0, stream>>>(w1, w2, w3, wbp);
    conv7f<<<dim3(1568), dim3(256), 0, stream>>>(x, wbp, outp);
  }
}

// Round 8
// 70.949 us; speedup vs baseline: 1.3136x; 1.0576x over previous
//
#include <hip/hip_runtime.h>
#include <cstdint>

typedef __attribute__((ext_vector_type(4))) int i32x4;

#define XROWS  22
#define ROWB   2048              // LDS bytes per staged row (w 0..31, 64B each)
#define WSLICE 8192
#define WB_BYTES 409600          // wb (401408) rounded up
#define XT_BYTES ((size_t)16 * 112 * 128 * 64)
#define NTILES 1568
#define GRID_MAIN 1536           // 2 exact layers at 3 blocks/CU; first 32 blocks dual

__device__ __forceinline__ void g2lds16(const void* g, void* l) {
  __builtin_amdgcn_global_load_lds(
      (const __attribute__((address_space(1))) unsigned int*)g,
      (__attribute__((address_space(3))) unsigned int*)l, 16, 0, 0);
}

// ---- standalone W pack (fallback path): wb[((s*4+g)*128+co)*16+lo], s=kh*7+kw
__global__ void prep_w(const float* __restrict__ w1,
                       const float* __restrict__ w2,
                       const float* __restrict__ w3,
                       signed char* __restrict__ wb) {
  int t = blockIdx.x * 256 + threadIdx.x;
  int lo = t & 15;
  int co = (t >> 4) & 127;
  int g  = (t >> 11) & 3;
  int s  = t >> 13;
  if (s >= 49) return;
  int kh = s / 7, kw = s % 7;
  int ci = g * 16 + lo;
  int base = ((co * 64 + ci) * 7 + kh) * 3;
  float v;
  if (kw < 3)       v = w1[base + kw];
  else if (kw == 3) v = w2[base + 1];
  else              v = w3[base + kw - 4];
  wb[t] = (signed char)(int)v;
}

// ---- merged prep: X pre-transpose + W pack.
// xt[n][h][w(128)][ci(64)] i8, clamped, 16B-granule-swizzled (granule p holds
// ci-granule p ^ ((w>>1)&3)).
__global__ void prep_xw(const int* __restrict__ x,
                        const float* __restrict__ w1,
                        const float* __restrict__ w2,
                        const float* __restrict__ w3,
                        signed char* __restrict__ xt,
                        signed char* __restrict__ wb) {
  __shared__ unsigned char T[64 * 68];
  const int tid = threadIdx.x;
  const int wt = blockIdx.x * 64, h = blockIdx.y, n = blockIdx.z;
  const int fid = (blockIdx.z * 112 + blockIdx.y) * 2 + blockIdx.x;

  if (fid < 1568) {                              // W pack: 1568*256 = 401408 elems
    int t = fid * 256 + tid;
    int lo = t & 15;
    int co = (t >> 4) & 127;
    int g  = (t >> 11) & 3;
    int s  = t >> 13;
    int kh = s / 7, kw = s % 7;
    int ci = g * 16 + lo;
    int base = ((co * 64 + ci) * 7 + kh) * 3;
    float v;
    if (kw < 3)       v = w1[base + kw];
    else if (kw == 3) v = w2[base + 1];
    else              v = w3[base + kw - 4];
    wb[t] = (signed char)(int)v;
  }

  {
    const int wr = tid & 63;
    const int cb = (tid >> 6) * 16;
    int ws = wt + wr; ws = ws < 112 ? ws : 111;
    const int* xp = x + (((size_t)n * 64 + cb) * 112 + h) * 112 + ws;
    #pragma unroll
    for (int g4 = 0; g4 < 4; ++g4) {
      uint32_t v = 0;
      #pragma unroll
      for (int j = 0; j < 4; ++j) {
        int a = xp[(g4 * 4 + j) * 12544];
        a = a < 0 ? 0 : (a > 7 ? 7 : a);
        v |= (uint32_t)a << (8 * j);
      }
      *(uint32_t*)&T[wr * 68 + cb + g4 * 4] = v;
    }
  }
  __syncthreads();
  {
    const int wo = tid >> 2, q = tid & 3;
    const int key = ((wt + wo) >> 1) & 3;
    const int sg = (q ^ key) << 4;
    int4 v;
    v.x = *(const int*)&T[wo * 68 + sg + 0];
    v.y = *(const int*)&T[wo * 68 + sg + 4];
    v.z = *(const int*)&T[wo * 68 + sg + 8];
    v.w = *(const int*)&T[wo * 68 + sg + 12];
    *(int4*)&xt[(((size_t)n * 112 + h) * 128 + wt + wo) * 64 + q * 16] = v;
  }
}

#define MFMA(acc, a, b) acc = __builtin_amdgcn_mfma_i32_16x16x64_i8(a, b, acc, 0, 0, 0)

// ---- main conv: static grid 1536 (+32 dual blocks). Wave = co16 x ho16 x wo16:
// 1 A-load + 16 MFMA per slice, B in a 16-deep register ring across kh.
__global__ __launch_bounds__(256, 3)
void conv7s(const signed char* __restrict__ xt,
            const signed char* __restrict__ wb,
            float* __restrict__ out) {
  __shared__ __align__(16) unsigned char Xs[XROWS * ROWB];   // 45056 B

  const int tid  = threadIdx.x;
  const int lane = tid & 63;
  const int wid  = tid >> 6;               // wave = co16 quarter of co64
  const int lrow = lane & 15;
  const int lkg  = lane >> 4;

  // bijective XCD chunking: 1536 = 8 * 192
  const int L  = blockIdx.x;
  const int Lp = (L & 7) * 192 + (L >> 3);
  const int npass = (L < 32) ? 2 : 1;

  for (int pass = 0; pass < npass; ++pass) {
    const int t = (pass == 0) ? Lp : (GRID_MAIN + L);   // tiles 1536..1567 on dual blocks
    const int coh = t & 1;
    const int r2  = t >> 1;
    const int bx  = r2 % 7;
    const int t7  = r2 / 7;
    const int by  = t7 % 7;
    const int n   = t7 / 7;
    const int ho_base = by * 16;
    const int wo_base = bx * 16;

    // A-frag base: wb addr = s*8192 + g*2048 + co*16 + lo; co = coh*64+wid*16+lrow
    const signed char* aB = wb + lkg * 2048 + (coh * 64 + wid * 16 + lrow) * 16;

    i32x4 Aa = *(const i32x4*)aB;        // slice (kh=0, kw=0)
    i32x4 Ab;

    if (pass) __syncthreads();           // protect Xs reuse across passes

    for (int r = wid; r < XROWS; r += 4) {
      int h = ho_base + r; h = h < 112 ? h : 111;   // clamped rows feed only masked outputs
      const signed char* src = xt + (((size_t)n * 112 + h) * 128 + wo_base) * 64;
      g2lds16(src + lane * 16, &Xs[r * ROWB]);
      g2lds16(src + 1024 + lane * 16, &Xs[r * ROWB + 1024]);
    }
    asm volatile("s_waitcnt vmcnt(0)" ::: "memory");
    __syncthreads();

    i32x4 acc[16];
    #pragma unroll
    for (int j = 0; j < 16; ++j) acc[j] = (i32x4){0, 0, 0, 0};

    for (int kw = 0; kw < 7; ++kw) {
      const int w_l  = lrow + kw;
      const int bcol = w_l * 64 + ((lkg ^ ((w_l >> 1) & 3)) << 4);
      i32x4 B[16];                        // ring: slot r&15 holds row r
      #pragma unroll
      for (int b = 0; b < 16; ++b)
        B[b] = *(const i32x4*)&Xs[b * ROWB + bcol];

      #pragma unroll
      for (int kh = 0; kh < 7; ++kh) {
        // prefetch A for next slice: (kh+1,kw) or (0,kw+1); s = kh*7+kw
        const signed char* apn =
            aB + (size_t)(kh < 6 ? (kh + 1) * 7 + kw : (kw < 6 ? kw + 1 : 0)) * WSLICE;
        __builtin_amdgcn_s_setprio(1);
        if ((kh & 1) == 0) {
          Ab = *(const i32x4*)apn;
          #pragma unroll
          for (int j = 0; j < 16; ++j)
            MFMA(acc[j], Aa, B[(kh + j) & 15]);
        } else {
          Aa = *(const i32x4*)apn;
          #pragma unroll
          for (int j = 0; j < 16; ++j)
            MFMA(acc[j], Ab, B[(kh + j) & 15]);
        }
        __builtin_amdgcn_s_setprio(0);
        if (kh < 6)                       // row kh dead; bring row kh+16 into slot kh
          B[kh] = *(const i32x4*)&Xs[(kh + 16) * ROWB + bcol];
      }
      Aa = Ab;                            // kh=6 (even) loaded next-kw slice into Ab
    }

    // epilogue: C/D map col=lane&15 (wo), row=(lane>>4)*4+jj (co); i32->f32 exact
    const int wo = wo_base + lrow;
    if (wo < 106) {
      const int co = coh * 64 + wid * 16 + lkg * 4;
      #pragma unroll
      for (int j = 0; j < 16; ++j) {
        const int ho = ho_base + j;
        if (ho < 106) {
          float* op = out + (((size_t)n * 128 + co) * 106 + ho) * 106 + wo;
          #pragma unroll
          for (int jj = 0; jj < 4; ++jj)
            op[(size_t)jj * 11236] = (float)acc[j][jj];
        }
      }
    }
  }
}

// ---- fallback (small ws): static grid 1568, stages straight from NCHW x
__global__ __launch_bounds__(256, 3)
void conv7f(const int* __restrict__ x,
            const signed char* __restrict__ wb, float* __restrict__ out) {
  __shared__ __align__(16) unsigned char Xs[XROWS * ROWB];

  const int tid  = threadIdx.x;
  const int lane = tid & 63;
  const int wid  = tid >> 6;
  const int lrow = lane & 15;
  const int lkg  = lane >> 4;

  const int L  = blockIdx.x;
  const int Lp = (L & 7) * 196 + (L >> 3);
  const int coh = Lp & 1;
  const int r2  = Lp >> 1;
  const int bx  = r2 % 7;
  const int t7  = r2 / 7;
  const int by  = t7 % 7;
  const int n   = t7 / 7;
  const int ho_base = by * 16;
  const int wo_base = bx * 16;

  const signed char* aB = wb + lkg * 2048 + coh * 1024 + lrow * 16;
  i32x4 A[4];
  #pragma unroll
  for (int m = 0; m < 4; ++m) A[m] = *(const i32x4*)(aB + m * 256);

  {
    const int w_a  = tid & 15,       cg_a  = tid >> 4;
    const int w_b2 = 16 + (tid & 7), cg_b2 = tid >> 3;
    const bool doB = (tid < 128) && ((tid & 7) < 6);
    const int keyA = ((w_a >> 1) & 3) << 2;
    const int keyB = ((w_b2 >> 1) & 3) << 2;
    for (int r = 0; r < XROWS; ++r) {
      int h = ho_base + r; h = h < 112 ? h : 111;
      const int* xr = x + (size_t)n * 64 * 12544 + h * 112;
      {
        int wc = wo_base + w_a; wc = wc < 112 ? wc : 111;
        uint32_t v = 0;
        #pragma unroll
        for (int j = 0; j < 4; ++j) {
          int a = xr[(cg_a * 4 + j) * 12544 + wc];
          a = a < 0 ? 0 : (a > 7 ? 7 : a);
          v |= (uint32_t)a << (8 * j);
        }
        *(uint32_t*)&Xs[r * ROWB + w_a * 64 + ((cg_a ^ keyA) << 2)] = v;
      }
      if (doB) {
        int wc = wo_base + w_b2; wc = wc < 112 ? wc : 111;
        uint32_t v = 0;
        #pragma unroll
        for (int j = 0; j < 4; ++j) {
          int a = xr[(cg_b2 * 4 + j) * 12544 + wc];
          a = a < 0 ? 0 : (a > 7 ? 7 : a);
          v |= (uint32_t)a << (8 * j);
        }
        *(uint32_t*)&Xs[r * ROWB + w_b2 * 64 + ((cg_b2 ^ keyB) << 2)] = v;
      }
    }
  }
  __syncthreads();

  i32x4 acc[4][4];
  #pragma unroll
  for (int m = 0; m < 4; ++m)
    #pragma unroll
    for (int b = 0; b < 4; ++b)
      acc[m][b] = (i32x4){0, 0, 0, 0};

  const int rowB = wid * 4;

  for (int kw = 0; kw < 7; ++kw) {
    const int w_l  = lrow + kw;
    const int bcol = w_l * 64 + ((lkg ^ ((w_l >> 1) & 3)) << 4);
    i32x4 B[8];
    #pragma unroll
    for (int b = 0; b < 4; ++b)
      B[b] = *(const i32x4*)&Xs[(rowB + b) * ROWB + bcol];
    #pragma unroll
    for (int kh = 0; kh < 7; ++kh) {
      if (kh < 6)
        B[(kh + 4) & 7] = *(const i32x4*)&Xs[(rowB + kh + 4) * ROWB + bcol];
      const signed char* apn = aB + (size_t)(kh < 6 ? (kh + 1) * 7 + kw : kw + 1) * WSLICE;
      #pragma unroll
      for (int m = 0; m < 4; ++m) {
        #pragma unroll
        for (int b = 0; b < 4; ++b)
          MFMA(acc[m][b], A[m], B[(kh + b) & 7]);
        A[m] = *(const i32x4*)(apn + m * 256);
      }
    }
  }

  const int wo = wo_base + lrow;
  if (wo < 106) {
    #pragma unroll
    for (int m = 0; m < 4; ++m) {
      const int co = coh * 64 + m * 16 + lkg * 4;
      #pragma unroll
      for (int b = 0; b < 4; ++b) {
        const int ho = ho_base + rowB + b;
        if (ho < 106) {
          float* op = out + (((size_t)n * 128 + co) * 106 + ho) * 106 + wo;
          #pragma unroll
          for (int j = 0; j < 4; ++j)
            op[(size_t)j * 11236] = (float)acc[m][b][j];
        }
      }
    }
  }
}

extern "C" void kernel_launch(void* const* d_in, const int* in_sizes, int n_in,
                              void* d_out, int out_size, void* d_ws, size_t ws_size,
                              hipStream_t stream) {
  const int*   x  = (const int*)d_in[0];
  const float* w1 = (const float*)d_in[1];
  const float* w2 = (const float*)d_in[2];
  const float* w3 = (const float*)d_in[3];
  float* outp = (float*)d_out;
  signed char* wbp = (signed char*)d_ws;
  signed char* xtp = wbp + WB_BYTES;

  if (ws_size >= WB_BYTES + XT_BYTES) {
    prep_xw<<<dim3(2, 112, 16), dim3(256), 0, stream>>>(x, w1, w2, w3, xtp, wbp);
    conv7s<<<dim3(GRID_MAIN), dim3(256), 0, stream>>>(xtp, wbp, outp);
  } else {
    prep_w<<<dim3(1568), dim3(256), 0, stream>>>(w1, w2, w3, wbp);
    conv7f<<<dim3(1568), dim3(256), 0, stream>>>(x, wbp, outp);
  }
}